// Round 19
// baseline (78.476 us; speedup 1.0000x reference)
//
#include <hip/hip_runtime.h>
#include <math.h>

#define NTOT 32768
#define NPG  2048
#define INDIM 32
#define HID  128
#define OUTD 64
#define NPAIR 100000
#define NEG_SLOPE 0.2f

typedef short bf16x8 __attribute__((ext_vector_type(8)));
typedef float f32x4 __attribute__((ext_vector_type(4)));

static __device__ __forceinline__ float b2f(ushort u) {
  return __uint_as_float(((unsigned)u) << 16);
}
static __device__ __forceinline__ ushort f2b(float f) {
  unsigned u = __float_as_uint(f);
  unsigned r = (u + 0x7fffu + ((u >> 16) & 1u)) >> 16;   // RNE
  return (ushort)r;
}
// chunk-swizzle: permute 8-bf16 (16B) chunks within each aligned 64-col group
// by row&7.  Involution; producers write swizzled global layout, GEMM stages
// linearly via global_load_lds, readers XOR on the LDS offset.
static __device__ __forceinline__ int swz_col(int row, int col) {
  return (col & ~63) | ((((col >> 3) ^ row) & 7) << 3) | (col & 7);
}
static __device__ __forceinline__ void gll16(const void* g, char* l) {
  __builtin_amdgcn_global_load_lds(
      (const __attribute__((address_space(1))) void*)g,
      (__attribute__((address_space(3))) void*)l, 16, 0, 0);
}

// ---------------------------------------------------------------------------
// MFMA prep: h = x@linW + b ; xl = h@gatW   (both split-bf16 3-term)
// gatW fragments read directly from global (plain transposed, L2-resident).
// (verbatim from round 18, passing)
// ---------------------------------------------------------------------------
#define HSTR 136
#define XSTR 40
#define PREP_LDS (34816 * 2)

__global__ __launch_bounds__(256) void prep_mfma_kernel(
    const float* __restrict__ x,
    const ushort* __restrict__ lwThi, const ushort* __restrict__ lwTlo,
    const float* __restrict__ linb,
    const ushort* __restrict__ gwThi, const ushort* __restrict__ gwTlo,
    float* __restrict__ xl)
{
  extern __shared__ __align__(16) char lds[];
  char* HS_HI = lds;
  char* HS_LO = lds + 34816;
  char* XS_HI = lds;
  char* XS_LO = lds + 10240;

  const int t = threadIdx.x;
  const int wv = t >> 6, lane = t & 63;
  const int frow = lane & 15, kq = lane >> 4;
  const int wr = (wv >> 1) * 64;
  const int wc = (wv & 1) * 64;
  const int m0 = blockIdx.x * 128;

  {
    const int row = t >> 1, hf = t & 1;
#pragma unroll
    for (int q = 0; q < 4; ++q) {
      const float4 v = *(const float4*)&x[(size_t)(m0 + row) * INDIM + hf * 16 + q * 4];
      ushort4 hi, lo;
      hi.x = f2b(v.x); lo.x = f2b(v.x - b2f(hi.x));
      hi.y = f2b(v.y); lo.y = f2b(v.y - b2f(hi.y));
      hi.z = f2b(v.z); lo.z = f2b(v.z - b2f(hi.z));
      hi.w = f2b(v.w); lo.w = f2b(v.w - b2f(hi.w));
      const int off = row * (XSTR * 2) + (hf * 16 + q * 4) * 2;
      *(ushort4*)(XS_HI + off) = hi;
      *(ushort4*)(XS_LO + off) = lo;
    }
  }
  __syncthreads();

  f32x4 acc1[4][4];
  {
    bf16x8 ah[4], al[4], bh[4], bl[4];
#pragma unroll
    for (int fr = 0; fr < 4; ++fr) {
      const int r = wr + fr * 16 + frow;
      const int off = r * (XSTR * 2) + kq * 16;
      ah[fr] = *(const bf16x8*)(XS_HI + off);
      al[fr] = *(const bf16x8*)(XS_LO + off);
    }
#pragma unroll
    for (int fc = 0; fc < 4; ++fc) {
      const int col = wc + fc * 16 + frow;
      bh[fc] = *(const bf16x8*)(lwThi + (size_t)col * 32 + kq * 8);
      bl[fc] = *(const bf16x8*)(lwTlo + (size_t)col * 32 + kq * 8);
    }
#pragma unroll
    for (int fr = 0; fr < 4; ++fr)
#pragma unroll
      for (int fc = 0; fc < 4; ++fc) {
        f32x4 a = (f32x4){0.f, 0.f, 0.f, 0.f};
        a = __builtin_amdgcn_mfma_f32_16x16x32_bf16(ah[fr], bh[fc], a, 0, 0, 0);
        a = __builtin_amdgcn_mfma_f32_16x16x32_bf16(ah[fr], bl[fc], a, 0, 0, 0);
        a = __builtin_amdgcn_mfma_f32_16x16x32_bf16(al[fr], bh[fc], a, 0, 0, 0);
        acc1[fr][fc] = a;
      }
  }
  __syncthreads();

#pragma unroll
  for (int fr = 0; fr < 4; ++fr)
#pragma unroll
    for (int fc = 0; fc < 4; ++fc) {
      const int col = wc + fc * 16 + frow;
      const float bj = linb[col];
#pragma unroll
      for (int j = 0; j < 4; ++j) {
        const int row = wr + fr * 16 + kq * 4 + j;
        const float v = acc1[fr][fc][j] + bj;
        const ushort hi = f2b(v);
        const int off = row * (HSTR * 2) + col * 2;
        *(ushort*)(HS_HI + off) = hi;
        *(ushort*)(HS_LO + off) = f2b(v - b2f(hi));
      }
    }
  __syncthreads();

  f32x4 acc2[4][4];
#pragma unroll
  for (int fr = 0; fr < 4; ++fr)
#pragma unroll
    for (int fc = 0; fc < 4; ++fc) acc2[fr][fc] = (f32x4){0.f, 0.f, 0.f, 0.f};
#pragma unroll
  for (int ks = 0; ks < 4; ++ks) {
    const int k = ks * 32 + kq * 8;
    bf16x8 ah[4], al[4], bh[4], bl[4];
#pragma unroll
    for (int fr = 0; fr < 4; ++fr) {
      const int r = wr + fr * 16 + frow;
      const int off = r * (HSTR * 2) + k * 2;
      ah[fr] = *(const bf16x8*)(HS_HI + off);
      al[fr] = *(const bf16x8*)(HS_LO + off);
    }
#pragma unroll
    for (int fc = 0; fc < 4; ++fc) {
      const int col = wc + fc * 16 + frow;
      bh[fc] = *(const bf16x8*)(gwThi + (size_t)col * 128 + k);
      bl[fc] = *(const bf16x8*)(gwTlo + (size_t)col * 128 + k);
    }
#pragma unroll
    for (int fr = 0; fr < 4; ++fr)
#pragma unroll
      for (int fc = 0; fc < 4; ++fc) {
        acc2[fr][fc] = __builtin_amdgcn_mfma_f32_16x16x32_bf16(ah[fr], bh[fc], acc2[fr][fc], 0, 0, 0);
        acc2[fr][fc] = __builtin_amdgcn_mfma_f32_16x16x32_bf16(ah[fr], bl[fc], acc2[fr][fc], 0, 0, 0);
        acc2[fr][fc] = __builtin_amdgcn_mfma_f32_16x16x32_bf16(al[fr], bh[fc], acc2[fr][fc], 0, 0, 0);
      }
  }

#pragma unroll
  for (int fr = 0; fr < 4; ++fr)
#pragma unroll
    for (int fc = 0; fc < 4; ++fc)
#pragma unroll
      for (int j = 0; j < 4; ++j) {
        const int row = m0 + wr + fr * 16 + kq * 4 + j;
        const int col = wc + fc * 16 + frow;
        xl[(size_t)row * HID + col] = acc2[fr][fc][j];
      }
}

// ---------------------------------------------------------------------------
// asrc/adst: one wave per node, float4-vectorized loads, shuffle reduce
// ---------------------------------------------------------------------------
__global__ __launch_bounds__(256) void reduce_kernel(
    const float* __restrict__ xl, const float* __restrict__ attS,
    const float* __restrict__ attD, float* __restrict__ asrc,
    float* __restrict__ adst)
{
  const int n = blockIdx.x * 4 + (threadIdx.x >> 6);
  const int l = threadIdx.x & 63;
  const float2 xv = *(const float2*)&xl[(size_t)n * HID + l * 2];
  const float2 sv = *(const float2*)&attS[l * 2];
  const float2 dv = *(const float2*)&attD[l * 2];
  float s = fmaf(xv.x, sv.x, xv.y * sv.y);
  float d = fmaf(xv.x, dv.x, xv.y * dv.y);
#pragma unroll
  for (int sh = 32; sh > 0; sh >>= 1) {
    s += __shfl_xor(s, sh, 64);
    d += __shfl_xor(d, sh, 64);
  }
  if (l == 0) { asrc[n] = s; adst[n] = d; }
}

// ---------------------------------------------------------------------------
// MEGA v7 (verbatim from round 18, passing): attention + 3-layer MLP fused,
// 64 rows/block, 1024 thr = 16 waves, swapped MFMAs (D^T, ushort4 epilogues).
// LDS: R1 ghi 16K | R2 64K (xl+hub -> e1 -> W3) | R3 64K (W dbuf -> e2)
// ---------------------------------------------------------------------------
#define R1O 0
#define R2O 16384
#define R3O 81920
#define RWR 147456
#define RGB 152064
#define MEGA_LDS 152576

__global__ __launch_bounds__(1024) void mega_kernel(
    const float* __restrict__ xl, const float* __restrict__ asrc,
    const float* __restrict__ adst, const float* __restrict__ gatb,
    const ushort* __restrict__ wt1hi, const ushort* __restrict__ wt2hi,
    const ushort* __restrict__ wt3hi,
    const float* __restrict__ b1, const float* __restrict__ b2,
    const float* __restrict__ b3, ushort* __restrict__ embb)
{
  extern __shared__ __align__(16) char lds[];
  const int t = threadIdx.x;
  const int wv = t >> 6, lane = t & 63;
  const int frow = lane & 15, kq = lane >> 4;
  const int wrow = (wv >> 3) * 32;
  const int wq = wv & 7;
  const int m0 = blockIdx.x * 64;
  const int gb = m0 & ~(NPG - 1);

  // ---- stage: xl tile (32KB), hub rows (12KB), W1 quarter0 -> R3 half0 ----
#pragma unroll
  for (int i = 0; i < 2; ++i) {
    const int c = t + i * 1024;
    gll16(xl + (size_t)(m0 + (c >> 5)) * HID + (c & 31) * 4,
          lds + R2O + i * 16384 + wv * 1024);
  }
  if (t < 768)
    gll16(xl + (size_t)(gb + (t >> 5)) * HID + (t & 31) * 4,
          lds + R2O + 32768 + wv * 1024);
#pragma unroll
  for (int i = 0; i < 2; ++i) {
    const int c = t + i * 1024;
    gll16(wt1hi + (size_t)(c >> 4) * 128 + (c & 15) * 8,
          lds + R3O + i * 16384 + wv * 1024);
  }
  if (t >= 64 && t < 192) ((float*)(lds + RGB))[t - 64] = gatb[t - 64];

  // ---- softmax weights (wave 0, one row per lane, 64 rows) ----
  float* wr = (float*)(lds + RWR);
  if (t < 64) {
    const int n = m0 + t;
    const int loc = n & (NPG - 1);
    float a[17];
#pragma unroll
    for (int k = 0; k < 17; ++k) {
      int c;
      if (k < 16) { const int nb = (loc < 16) ? ((k < loc) ? k : k + 1) : k; c = gb + nb; }
      else c = n;
      a[k] = asrc[c];
    }
    const float ad = adst[n];
    float m = -__builtin_inff();
#pragma unroll
    for (int k = 0; k < 17; ++k) {
      float l = a[k] + ad;
      l = (l > 0.f) ? l : NEG_SLOPE * l;
      m = fmaxf(m, l);
    }
    float den = 0.f;
#pragma unroll
    for (int k = 0; k < 17; ++k) {
      float l = a[k] + ad;
      l = (l > 0.f) ? l : NEG_SLOPE * l;
      const float w = __expf(l - m);
      wr[t * 18 + k] = w;
      den += w;
    }
    wr[t * 18 + 17] = 1.f / den;
  }
  __syncthreads();

  // ---- weighted sum -> ghi tile (R1, bf16 swizzled); hub values hoisted ----
  {
    const float* xs = (const float*)(lds + R2O);
    const float* hs = (const float*)(lds + R2O + 32768);
    const int j = t & 127;
    const int r0 = t >> 7;
    const float gj = ((const float*)(lds + RGB))[j];
    float hb[17];
#pragma unroll
    for (int k = 0; k < 17; ++k) hb[k] = hs[k * 128 + j];
    const bool basel = (m0 & (NPG - 1)) == 0;
#pragma unroll
    for (int oi = 0; oi < 8; ++oi) {
      const int r = r0 + oi * 8;
      float acc = 0.f;
      if (basel && r < 16) {
#pragma unroll
        for (int k = 0; k < 16; ++k)
          acc = fmaf(wr[r * 18 + k], (k < r) ? hb[k] : hb[k + 1], acc);
      } else {
#pragma unroll
        for (int k = 0; k < 16; ++k)
          acc = fmaf(wr[r * 18 + k], hb[k], acc);
      }
      acc = fmaf(wr[r * 18 + 16], xs[r * 128 + j], acc);
      const float v = acc * wr[r * 18 + 17] + gj;
      const int off = r * 256 + ((j >> 6) << 7) + ((((j >> 3) & 7) ^ (r & 7)) << 4) + ((j & 7) << 1);
      *(ushort*)(lds + R1O + off) = f2b(v);
    }
  }
  __syncthreads();

  // ---- hoist ghi A-fragments (invariant across phase-1 quarters) ----
  bf16x8 af_all[2][4];
#pragma unroll
  for (int fr = 0; fr < 2; ++fr)
#pragma unroll
    for (int ks = 0; ks < 4; ++ks) {
      const int cc = ks * 4 + kq;
      const int r = wrow + fr * 16 + frow;
      af_all[fr][ks] = *(const bf16x8*)(lds + R1O + r * 256 + ((cc >> 3) << 7) + (((cc & 7) ^ (r & 7)) << 4));
    }

  // ---- phase 1: e1 = relu(ghi @ W1 + b1), swapped mfma ----
#pragma unroll 1
  for (int q = 0; q < 4; ++q) {
    if (q < 3) {
      char* dst = lds + R3O + ((q + 1) & 1) * 32768;
#pragma unroll
      for (int i = 0; i < 2; ++i) {
        const int c = t + i * 1024;
        gll16(wt1hi + (size_t)((q + 1) * 128 + (c >> 4)) * 128 + (c & 15) * 8,
              dst + i * 16384 + wv * 1024);
      }
    } else {
#pragma unroll
      for (int i = 0; i < 2; ++i) {
        const int c = t + i * 1024;
        gll16(wt2hi + (size_t)(c >> 3) * 512 + (c & 7) * 8,
              lds + R3O + i * 16384 + wv * 1024);
      }
    }
    char* Bq = lds + R3O + (q & 1) * 32768;
    f32x4 acc[2];
#pragma unroll
    for (int fr = 0; fr < 2; ++fr) acc[fr] = (f32x4){0.f, 0.f, 0.f, 0.f};
    __builtin_amdgcn_s_setprio(1);
#pragma unroll
    for (int ks = 0; ks < 4; ++ks) {
      const int cc = ks * 4 + kq;
      const int rb = wq * 16 + frow;
      const bf16x8 bf = *(const bf16x8*)(Bq + rb * 256 + ((cc >> 3) << 7) + (((cc & 7) ^ (rb & 7)) << 4));
#pragma unroll
      for (int fr = 0; fr < 2; ++fr)
        acc[fr] = __builtin_amdgcn_mfma_f32_16x16x32_bf16(bf, af_all[fr][ks], acc[fr], 0, 0, 0);
    }
    __builtin_amdgcn_s_setprio(0);
#pragma unroll
    for (int fr = 0; fr < 2; ++fr) {
      const int row = wrow + fr * 16 + frow;
      const int colb = q * 128 + wq * 16 + kq * 4;
      const float4 bb = *(const float4*)&b1[colb];
      ushort4 o;
      o.x = f2b(fmaxf(acc[fr][0] + bb.x, 0.f));
      o.y = f2b(fmaxf(acc[fr][1] + bb.y, 0.f));
      o.z = f2b(fmaxf(acc[fr][2] + bb.z, 0.f));
      o.w = f2b(fmaxf(acc[fr][3] + bb.w, 0.f));
      const int off = row * 1024 + ((colb >> 6) << 7) + ((((colb >> 3) & 7) ^ (row & 7)) << 4) + ((colb & 7) << 1);
      *(ushort4*)(lds + R2O + off) = o;
    }
    __syncthreads();
  }

  // ---- phase 2: e2 = relu(e1 @ W2 + b2), K=512, 8 pipelined chunks ----
  f32x4 acc2[2][2];
#pragma unroll
  for (int fr = 0; fr < 2; ++fr)
#pragma unroll
    for (int fc = 0; fc < 2; ++fc) acc2[fr][fc] = (f32x4){0.f, 0.f, 0.f, 0.f};
#pragma unroll 1
  for (int kc = 0; kc < 8; ++kc) {
    if (kc < 7) {
      char* dst = lds + R3O + ((kc + 1) & 1) * 32768;
#pragma unroll
      for (int i = 0; i < 2; ++i) {
        const int c = t + i * 1024;
        gll16(wt2hi + (size_t)(c >> 3) * 512 + (kc + 1) * 64 + (c & 7) * 8,
              dst + i * 16384 + wv * 1024);
      }
    }
    char* Bb = lds + R3O + (kc & 1) * 32768;
    __builtin_amdgcn_s_setprio(1);
#pragma unroll
    for (int ks = 0; ks < 2; ++ks) {
      const int cl = ks * 4 + kq;
      bf16x8 af[2], bf[2];
#pragma unroll
      for (int fr = 0; fr < 2; ++fr) {
        const int r = wrow + fr * 16 + frow;
        af[fr] = *(const bf16x8*)(lds + R2O + r * 1024 + (kc << 7) + ((cl ^ (r & 7)) << 4));
      }
#pragma unroll
      for (int fc = 0; fc < 2; ++fc) {
        const int rb = wq * 32 + fc * 16 + frow;
        bf[fc] = *(const bf16x8*)(Bb + rb * 128 + ((cl ^ (rb & 7)) << 4));
      }
#pragma unroll
      for (int fr = 0; fr < 2; ++fr)
#pragma unroll
        for (int fc = 0; fc < 2; ++fc)
          acc2[fr][fc] = __builtin_amdgcn_mfma_f32_16x16x32_bf16(bf[fc], af[fr], acc2[fr][fc], 0, 0, 0);
    }
    __builtin_amdgcn_s_setprio(0);
    __syncthreads();
  }
#pragma unroll
  for (int fr = 0; fr < 2; ++fr)
#pragma unroll
    for (int fc = 0; fc < 2; ++fc) {
      const int row = wrow + fr * 16 + frow;
      const int colb = wq * 32 + fc * 16 + kq * 4;
      const float4 bb = *(const float4*)&b2[colb];
      ushort4 o;
      o.x = f2b(fmaxf(acc2[fr][fc][0] + bb.x, 0.f));
      o.y = f2b(fmaxf(acc2[fr][fc][1] + bb.y, 0.f));
      o.z = f2b(fmaxf(acc2[fr][fc][2] + bb.z, 0.f));
      o.w = f2b(fmaxf(acc2[fr][fc][3] + bb.w, 0.f));
      const int off = row * 512 + ((colb >> 6) << 7) + ((((colb >> 3) & 7) ^ (row & 7)) << 4) + ((colb & 7) << 1);
      *(ushort4*)(lds + R3O + off) = o;
    }
#pragma unroll
  for (int i = 0; i < 2; ++i) {
    const int c = t + i * 1024;
    gll16(wt3hi + (size_t)(c >> 5) * 256 + (c & 31) * 8,
          lds + R2O + i * 16384 + wv * 1024);
  }
  __syncthreads();

  // ---- phase 3: emb = e2 @ W3 + b3; swapped mfma, ushort4 out ----
  {
    const int wr3 = (wv >> 2) * 16;
    const int wq3 = wv & 3;
    f32x4 acc3 = (f32x4){0.f, 0.f, 0.f, 0.f};
    __builtin_amdgcn_s_setprio(1);
#pragma unroll
    for (int ks = 0; ks < 8; ++ks) {
      const int cc = ks * 4 + kq;
      const int r = wr3 + frow;
      const bf16x8 af = *(const bf16x8*)(lds + R3O + r * 512 + ((cc >> 3) << 7) + (((cc & 7) ^ (r & 7)) << 4));
      const int rb = wq3 * 16 + frow;
      const bf16x8 bf = *(const bf16x8*)(lds + R2O + rb * 512 + ((cc >> 3) << 7) + (((cc & 7) ^ (rb & 7)) << 4));
      acc3 = __builtin_amdgcn_mfma_f32_16x16x32_bf16(bf, af, acc3, 0, 0, 0);
    }
    __builtin_amdgcn_s_setprio(0);
    const int row = m0 + wr3 + frow;
    const int colb = wq3 * 16 + kq * 4;
    ushort4 o;
    o.x = f2b(acc3[0] + b3[colb + 0]);
    o.y = f2b(acc3[1] + b3[colb + 1]);
    o.z = f2b(acc3[2] + b3[colb + 2]);
    o.w = f2b(acc3[3] + b3[colb + 3]);
    *(ushort4*)&embb[(size_t)row * OUTD + colb] = o;
  }
}

// ---------------------------------------------------------------------------
// fused weight conversion + pairs layout detection (one launch).
// Blocks 0..911: weight conversion.  Blocks 912..1011: pairs high-word scan
// (flag pre-zeroed via hipMemsetAsync before this kernel).
// ---------------------------------------------------------------------------
#define CONV_BLOCKS 912
#define DET_BLOCKS  100

__global__ __launch_bounds__(256) void convert_all_kernel(
    const float* __restrict__ W1, const float* __restrict__ W2,
    const float* __restrict__ W3, const float* __restrict__ linW,
    const float* __restrict__ gatW,
    ushort* __restrict__ wt1hi, ushort* __restrict__ wt2hi,
    ushort* __restrict__ wt3hi,
    ushort* __restrict__ lwThi, ushort* __restrict__ lwTlo,
    ushort* __restrict__ gwThi, ushort* __restrict__ gwTlo,
    const unsigned long long* __restrict__ p64, int* __restrict__ flag)
{
  if (blockIdx.x >= CONV_BLOCKS) {            // pairs layout detection
    __shared__ int s;
    if (threadIdx.x == 0) s = 0;
    __syncthreads();
    int loc = 0;
    for (int i = (blockIdx.x - CONV_BLOCKS) * 256 + threadIdx.x; i < NPAIR;
         i += DET_BLOCKS * 256)
      loc |= ((p64[i] >> 32) != 0ull) ? 1 : 0;
    if (loc) atomicOr(&s, 1);
    __syncthreads();
    if (threadIdx.x == 0 && s) atomicOr(flag, 1);
    return;
  }
  const int i = blockIdx.x * 256 + threadIdx.x;
  if (i < 65536) {                            // W1 [128][512] -> [512][128]
    const int k = i >> 9, n = i & 511;
    wt1hi[(size_t)n * 128 + swz_col(n, k)] = f2b(W1[i]);
  } else if (i < 196608) {                    // W2 [512][256] -> [256][512]
    const int j = i - 65536;
    const int k = j >> 8, n = j & 255;
    wt2hi[(size_t)n * 512 + swz_col(n, k)] = f2b(W2[j]);
  } else if (i < 212992) {                    // W3 [256][64] -> [64][256]
    const int j = i - 196608;
    const int k = j >> 6, n = j & 63;
    wt3hi[(size_t)n * 256 + swz_col(n, k)] = f2b(W3[j]);
  } else if (i < 217088) {                    // linW [32][128] -> [128][32]
    const int j = i - 212992;
    const int k = j >> 7, n = j & 127;
    const float v = linW[j];
    const ushort hi = f2b(v);
    lwThi[(size_t)n * 32 + k] = hi;
    lwTlo[(size_t)n * 32 + k] = f2b(v - b2f(hi));
  } else if (i < 233472) {                    // gatW [128][128] -> plain T
    const int j = i - 217088;
    const int k = j >> 7, n = j & 127;
    const float v = gatW[j];
    const ushort hi = f2b(v);
    gwThi[(size_t)n * 128 + k] = hi;
    gwTlo[(size_t)n * 128 + k] = f2b(v - b2f(hi));
  }
}

// ---------------------------------------------------------------------------
// final pair gather (fp32 out), 4-wide vectorized
// ---------------------------------------------------------------------------
__global__ __launch_bounds__(256) void gather_kernel(
    const ushort* __restrict__ embb, const unsigned long long* __restrict__ p64,
    const float* __restrict__ labels, const int* __restrict__ flagp,
    float* __restrict__ out)
{
  const int i4 = blockIdx.x * 256 + threadIdx.x;
  const int tot4 = 2 * NPAIR * OUTD / 4;
  if (i4 < tot4) {
    const int fl = *flagp;
    const int i = i4 * 4;
    const int which = i / (NPAIR * OUTD);
    const int rem = i - which * (NPAIR * OUTD);
    const int p = rem >> 6, j = rem & 63;      // j multiple of 4
    const int fi = p * 2 + which;
    int node;
    if (fl) {
      const unsigned long long w = p64[fi >> 1];
      node = (int)((fi & 1) ? (w >> 32) : (w & 0xffffffffull));
    } else {
      node = (int)p64[fi];
    }
    node &= (NTOT - 1);
    const ushort4 e = *(const ushort4*)&embb[(size_t)node * OUTD + j];
    float4 o;
    o.x = b2f(e.x); o.y = b2f(e.y); o.z = b2f(e.z); o.w = b2f(e.w);
    *(float4*)&out[i] = o;
  } else {
    const int li = i4 - tot4;
    if (li < NPAIR) out[2 * NPAIR * OUTD + li] = labels[li];
  }
}

extern "C" void kernel_launch(void* const* d_in, const int* in_sizes, int n_in,
                              void* d_out, int out_size, void* d_ws, size_t ws_size,
                              hipStream_t stream)
{
  const float* x      = (const float*)d_in[0];
  const unsigned long long* pairs = (const unsigned long long*)d_in[2];
  const float* labels = (const float*)d_in[3];
  const float* linW   = (const float*)d_in[4];
  const float* linb   = (const float*)d_in[5];
  const float* gatW   = (const float*)d_in[6];
  const float* attS   = (const float*)d_in[7];
  const float* attD   = (const float*)d_in[8];
  const float* gatb   = (const float*)d_in[9];
  const float* W1     = (const float*)d_in[10];
  const float* b1     = (const float*)d_in[11];
  const float* W2     = (const float*)d_in[12];
  const float* b2     = (const float*)d_in[13];
  const float* W3     = (const float*)d_in[14];
  const float* b3     = (const float*)d_in[15];

  float* ws = (float*)d_ws;
  const size_t NT = NTOT;
  float*  xl    = ws;                        // [0,128)
  ushort* embb  = (ushort*)(ws + NT * 128);  // [128,160)
  float*  asrc  = ws + NT * 160;
  float*  adst  = ws + NT * 161;
  ushort* wt1hi = (ushort*)(ws + NT * 162);  // [512][128] swz
  ushort* wt2hi = wt1hi + 512 * 128;         // [256][512] swz
  ushort* wt3hi = wt2hi + 256 * 512;         // [64][256]  swz
  ushort* lwThi = wt3hi + 64 * 256;          // [128][32] plain
  ushort* lwTlo = lwThi + 128 * 32;
  ushort* gwThi = lwTlo + 128 * 32;          // [128][128] plain
  ushort* gwTlo = gwThi + 128 * 128;
  int*    flag  = (int*)(gwTlo + 128 * 128);

  (void)hipFuncSetAttribute(
      reinterpret_cast<const void*>(prep_mfma_kernel),
      hipFuncAttributeMaxDynamicSharedMemorySize, PREP_LDS);
  (void)hipFuncSetAttribute(
      reinterpret_cast<const void*>(mega_kernel),
      hipFuncAttributeMaxDynamicSharedMemorySize, MEGA_LDS);

  (void)hipMemsetAsync(flag, 0, sizeof(int), stream);
  convert_all_kernel<<<CONV_BLOCKS + DET_BLOCKS, 256, 0, stream>>>(
      W1, W2, W3, linW, gatW, wt1hi, wt2hi, wt3hi,
      lwThi, lwTlo, gwThi, gwTlo, pairs, flag);

  prep_mfma_kernel<<<NTOT / 128, 256, PREP_LDS, stream>>>(
      x, lwThi, lwTlo, linb, gwThi, gwTlo, xl);
  reduce_kernel<<<NTOT / 4, 256, 0, stream>>>(xl, attS, attD, asrc, adst);

  mega_kernel<<<NTOT / 64, 1024, MEGA_LDS, stream>>>(
      xl, asrc, adst, gatb, wt1hi, wt2hi, wt3hi, b1, b2, b3, embb);

  const int total4 = 2 * NPAIR * OUTD / 4 + NPAIR;
  gather_kernel<<<(total4 + 255) / 256, 256, 0, stream>>>(embb, pairs, labels, flag, (float*)d_out);
}